// Round 6
// baseline (166.940 us; speedup 1.0000x reference)
//
#include <hip/hip_runtime.h>

#define Bz 2
#define Sz 2048
#define Dz 1024
#define Hz 16
#define HSz 64
#define Mz 4096
#define NEGB (-1e30f)
#define QSCALE (0.125f * 1.44269504088896f)  // fold 1/sqrt(64) and log2(e) into Q

typedef _Float16 f16;
typedef _Float16 f16x8 __attribute__((ext_vector_type(8)));
typedef _Float16 f16x4 __attribute__((ext_vector_type(4)));
typedef float f32x4 __attribute__((ext_vector_type(4)));

#define MFMA32(a, b, c) __builtin_amdgcn_mfma_f32_16x16x32_f16((a), (b), (c), 0, 0, 0)
#define MFMA16(a, b, c) __builtin_amdgcn_mfma_f32_16x16x16f16((a), (b), (c), 0, 0, 0)
#define EXP2(x) __builtin_amdgcn_exp2f(x)

__device__ __forceinline__ void gload16(const void* g, void* l) {
  __builtin_amdgcn_global_load_lds(
      (const __attribute__((address_space(1))) unsigned int*)(unsigned long long)g,
      (__attribute__((address_space(3))) unsigned int*)(unsigned int)(unsigned long long)l,
      16, 0, 0);
}
__device__ __forceinline__ void gload4(const void* g, void* l) {
  __builtin_amdgcn_global_load_lds(
      (const __attribute__((address_space(1))) unsigned int*)(unsigned long long)g,
      (__attribute__((address_space(3))) unsigned int*)(unsigned int)(unsigned long long)l,
      4, 0, 0);
}

// ---------------- fp32 -> fp16 convert, 3 tensors in one dispatch ----------------
__global__ __launch_bounds__(256) void k_cvt3(const float* __restrict__ a,
                                              const float* __restrict__ b,
                                              const float* __restrict__ c,
                                              f16* __restrict__ oa,
                                              f16* __restrict__ ob,
                                              f16* __restrict__ oc) {
  const float* in = blockIdx.y == 0 ? a : blockIdx.y == 1 ? b : c;
  f16* out = blockIdx.y == 0 ? oa : blockIdx.y == 1 ? ob : oc;
  int i = (blockIdx.x * 256 + threadIdx.x) * 4;
  f32x4 v = *reinterpret_cast<const f32x4*>(in + i);
  f16x4 o;
  o[0] = (f16)v[0]; o[1] = (f16)v[1]; o[2] = (f16)v[2]; o[3] = (f16)v[3];
  *reinterpret_cast<f16x4*>(out + i) = o;
}

// ---------------- v_mask -> f32 additive bias (exp2 domain) ----------------
__global__ __launch_bounds__(256) void k_mask(const int* __restrict__ vm,
                                              float* __restrict__ out) {
  int i = blockIdx.x * 256 + threadIdx.x;
  if (i < Bz * Sz) out[i] = vm[i] ? 0.f : NEGB;
}

// ---------------- W [K][N] fp32 -> Wt [N][K] fp16, 4 weights in one dispatch ----------------
__global__ __launch_bounds__(256) void k_wsplit4(
    const float* __restrict__ W0, const float* __restrict__ W1,
    const float* __restrict__ W2, const float* __restrict__ W3,
    f16* __restrict__ T0, f16* __restrict__ T1, f16* __restrict__ T2,
    f16* __restrict__ T3) {
  const int z = blockIdx.z;
  const float* W = z == 0 ? W0 : z == 1 ? W1 : z == 2 ? W2 : W3;
  f16* T = z == 0 ? T0 : z == 1 ? T1 : z == 2 ? T2 : T3;
  __shared__ float t[32][33];
  const int tx = threadIdx.x & 31, ty = threadIdx.x >> 5;
  const int n0 = blockIdx.x * 32, k0 = blockIdx.y * 32;
#pragma unroll
  for (int r = 0; r < 4; ++r)
    t[ty * 4 + r][tx] = W[(size_t)(k0 + ty * 4 + r) * Dz + n0 + tx];
  __syncthreads();
#pragma unroll
  for (int r = 0; r < 4; ++r)
    T[(size_t)(n0 + ty * 4 + r) * Dz + k0 + tx] = (f16)t[tx][ty * 4 + r];
}

// ---------------- GEMM main-loop (shared by QKV / O kernels) ----------------
#define BMg 128
#define BNg 128
#define BKg 64

#define GEMM_MAINLOOP(Aptr, Bptr)                                              \
  f32x4 acc[4][2] = {};                                                        \
  auto stage = [&](int kt, int buf) {                                          \
    const int k0 = kt * BKg;                                                   \
    _Pragma("unroll") for (int j = 0; j < 2; ++j) {                            \
      int c = j * 512 + t;                                                     \
      int row = c >> 3, p = c & 7;                                             \
      int ke = (p ^ (row & 7)) * 8;                                            \
      gload16(Aptr + (size_t)(m0 + row) * Dz + k0 + ke,                        \
              (char*)&As[buf][0] + c * 16);                                    \
      gload16(Bptr + (size_t)(n0 + row) * Dz + k0 + ke,                        \
              (char*)&Bs[buf][0] + c * 16);                                    \
    }                                                                          \
  };                                                                           \
  stage(0, 0);                                                                 \
  __syncthreads();                                                             \
  for (int kt = 0; kt < Dz / BKg; ++kt) {                                      \
    const int cur = kt & 1;                                                    \
    if (kt + 1 < Dz / BKg) stage(kt + 1, cur ^ 1);                             \
    __builtin_amdgcn_s_setprio(1);                                             \
    _Pragma("unroll") for (int ks = 0; ks < 2; ++ks) {                         \
      f16x8 af[4], bf[2];                                                      \
      _Pragma("unroll") for (int fr = 0; fr < 4; ++fr) {                       \
        const int row = wr * 64 + fr * 16 + ll;                                \
        af[fr] = *reinterpret_cast<const f16x8*>(                              \
            &As[cur][row * 64 + (((ks * 4 + lh) ^ (row & 7)) * 8)]);           \
      }                                                                        \
      _Pragma("unroll") for (int fc = 0; fc < 2; ++fc) {                       \
        const int col = wc * 32 + fc * 16 + ll;                                \
        bf[fc] = *reinterpret_cast<const f16x8*>(                              \
            &Bs[cur][col * 64 + (((ks * 4 + lh) ^ (col & 7)) * 8)]);           \
      }                                                                        \
      _Pragma("unroll") for (int fr = 0; fr < 4; ++fr)                         \
          _Pragma("unroll") for (int fc = 0; fc < 2; ++fc)                     \
              acc[fr][fc] = MFMA32(af[fr], bf[fc], acc[fr][fc]);               \
    }                                                                          \
    __builtin_amdgcn_s_setprio(0);                                             \
    __syncthreads();                                                           \
  }

// Merged Q/K/V projection GEMM: blockIdx.z selects input/weight/output.
__global__ __launch_bounds__(512) void k_gemm_qkv(
    const f16* __restrict__ Xq, const f16* __restrict__ Xk,
    const f16* __restrict__ Xv, const f16* __restrict__ Wq,
    const f16* __restrict__ Wk, const f16* __restrict__ Wv,
    const float* __restrict__ bq, const float* __restrict__ bk,
    const float* __restrict__ bv, f16* __restrict__ Qh, f16* __restrict__ Kh,
    f16* __restrict__ Vth) {
  __shared__ f16 As[2][BMg * BKg];
  __shared__ f16 Bs[2][BNg * BKg];
  const int z = blockIdx.z;
  const f16* A = z == 0 ? Xq : z == 1 ? Xk : Xv;
  const f16* Bt = z == 0 ? Wq : z == 1 ? Wk : Wv;
  const float* bias = z == 0 ? bq : z == 1 ? bk : bv;
  f16* outh = z == 0 ? Qh : z == 1 ? Kh : Vth;
  const float oscale = z == 0 ? QSCALE : 1.0f;
  const int t = threadIdx.x, lane = t & 63, wv = t >> 6;
  const int ll = lane & 15, lh = lane >> 4;
  const int m0 = blockIdx.y * BMg, n0 = blockIdx.x * BNg;
  const int wr = wv >> 2, wc = wv & 3;

  GEMM_MAINLOOP(A, Bt)

#pragma unroll
  for (int fc = 0; fc < 2; ++fc) {
    const int n = n0 + wc * 32 + fc * 16 + ll;
    const float bn = bias[n];
#pragma unroll
    for (int fr = 0; fr < 4; ++fr)
#pragma unroll
      for (int i = 0; i < 4; ++i) {
        const int m = m0 + wr * 64 + fr * 16 + lh * 4 + i;
        float v = (acc[fr][fc][i] + bn) * oscale;
        if (z < 2) {
          outh[((size_t)((m >> 11) * Hz + (n >> 6))) * (Sz * HSz) +
               (size_t)(m & (Sz - 1)) * HSz + (n & 63)] = (f16)v;
        } else {
          outh[((size_t)((m >> 11) * Hz + (n >> 6))) * (HSz * Sz) +
               (size_t)(n & 63) * Sz + (m & (Sz - 1))] = (f16)v;
        }
      }
  }
}

// Output projection GEMM: f32 out, * q_mask[row]
__global__ __launch_bounds__(512) void k_gemm_o(
    const f16* __restrict__ A, const f16* __restrict__ Bt,
    const float* __restrict__ bias, float* __restrict__ outf,
    const int* __restrict__ qmask) {
  __shared__ f16 As[2][BMg * BKg];
  __shared__ f16 Bs[2][BNg * BKg];
  const int t = threadIdx.x, lane = t & 63, wv = t >> 6;
  const int ll = lane & 15, lh = lane >> 4;
  const int m0 = blockIdx.y * BMg, n0 = blockIdx.x * BNg;
  const int wr = wv >> 2, wc = wv & 3;

  GEMM_MAINLOOP(A, Bt)

#pragma unroll
  for (int fc = 0; fc < 2; ++fc) {
    const int n = n0 + wc * 32 + fc * 16 + ll;
    const float bn = bias[n];
#pragma unroll
    for (int fr = 0; fr < 4; ++fr)
#pragma unroll
      for (int i = 0; i < 4; ++i) {
        const int m = m0 + wr * 64 + fr * 16 + lh * 4 + i;
        outf[(size_t)m * Dz + n] = (acc[fr][fc][i] + bn) * (float)qmask[m];
      }
  }
}

// ---------------- flash attention, S^T structure, K-split x2 ----------------
// Each block: 128 queries x 1024 keys (half = blockIdx.z). Partials:
// Op[half] = normalized O (f16), ml[half] = (m_run, l_run) per (bh, q).
// Mask bias initializes the QK^T accumulator (C-operand) - no VALU add.
#define QB 128
#define KBc 64
#define KSPLIT 2
#define NT2 (Sz / KSPLIT / KBc)

__global__ __launch_bounds__(512, 8) void k_attn(
    const f16* __restrict__ Q, const f16* __restrict__ K,
    const f16* __restrict__ Vt, const float* __restrict__ vmb,
    f16* __restrict__ Op0, f16* __restrict__ Op1, float2* __restrict__ ml) {
  __shared__ f16 Kl[2][KBc * 64];
  __shared__ f16 Vl[2][HSz * 64];
  __shared__ float mbl[2][KBc];
  const int t = threadIdx.x, lane = t & 63, wv = t >> 6;
  const int ll = lane & 15, lh = lane >> 4;
  const int bh = blockIdx.y, b = bh >> 4, h = bh & 15;
  const int q0 = blockIdx.x * QB;
  const int half = blockIdx.z;
  const int kbase = half * (Sz / KSPLIT);
  const size_t base = (size_t)bh * Sz * HSz;

  f16x8 qf[2];
  {
    const f16* Qb = Q + base + (size_t)(q0 + wv * 16 + ll) * HSz;
    qf[0] = *reinterpret_cast<const f16x8*>(&Qb[lh * 8]);
    qf[1] = *reinterpret_cast<const f16x8*>(&Qb[32 + lh * 8]);
  }

  f32x4 acc[4] = {};
  float m_run = NEGB, l_run = 0.f;

  auto stage = [&](int key0, int buf) {
    int c = wv * 64 + lane;
    int r = c >> 3, p = c & 7, ps = (p ^ (r & 7)) * 8;
    gload16(K + base + (size_t)(key0 + r) * HSz + ps, (char*)&Kl[buf][0] + c * 16);
    gload16(Vt + base + (size_t)r * Sz + key0 + ps, (char*)&Vl[buf][0] + c * 16);
    if (wv == 0)
      gload4(vmb + b * Sz + key0 + lane, (char*)&mbl[buf][0] + lane * 4);
  };

  stage(kbase, 0);
  __syncthreads();

  for (int kt = 0; kt < NT2; ++kt) {
    const int cur = kt & 1;
    if (kt + 1 < NT2) stage(kbase + (kt + 1) * KBc, cur ^ 1);

    // S^T = K * Q^T, accumulator initialized with the mask bias
    f32x4 sa[4];
#pragma unroll
    for (int cf = 0; cf < 4; ++cf)
      sa[cf] = *reinterpret_cast<const f32x4*>(&mbl[cur][cf * 16 + lh * 4]);
    __builtin_amdgcn_s_setprio(1);
#pragma unroll
    for (int cf = 0; cf < 4; ++cf) {
      const int row = cf * 16 + ll;
      const f16* kr = &Kl[cur][row * 64];
      f16x8 ka0 = *reinterpret_cast<const f16x8*>(&kr[(lh ^ (ll & 7)) * 8]);
      f16x8 ka1 = *reinterpret_cast<const f16x8*>(&kr[((4 + lh) ^ (ll & 7)) * 8]);
      sa[cf] = MFMA32(ka0, qf[0], sa[cf]);
      sa[cf] = MFMA32(ka1, qf[1], sa[cf]);
    }
    __builtin_amdgcn_s_setprio(0);

    // max via max3-friendly triples
    float t0 = fmaxf(fmaxf(sa[0][0], sa[0][1]), sa[0][2]);
    float t1 = fmaxf(fmaxf(sa[0][3], sa[1][0]), sa[1][1]);
    float t2 = fmaxf(fmaxf(sa[1][2], sa[1][3]), sa[2][0]);
    float t3 = fmaxf(fmaxf(sa[2][1], sa[2][2]), sa[2][3]);
    float t4 = fmaxf(fmaxf(sa[3][0], sa[3][1]), sa[3][2]);
    float mx = fmaxf(fmaxf(fmaxf(t0, t1), fmaxf(t2, t3)), fmaxf(t4, sa[3][3]));
    mx = fmaxf(mx, __shfl_xor(mx, 16));
    mx = fmaxf(mx, __shfl_xor(mx, 32));
    if (__any(mx > m_run + 8.f)) {
      const float nm = fmaxf(m_run, mx);
      const float sc = EXP2(m_run - nm);
      m_run = nm;
      l_run *= sc;
#pragma unroll
      for (int hf = 0; hf < 4; ++hf)
#pragma unroll
        for (int i = 0; i < 4; ++i) acc[hf][i] *= sc;
    }
    float rs0 = 0.f, rs1 = 0.f;
    f16x4 pb[4];
#pragma unroll
    for (int cf = 0; cf < 4; ++cf) {
      float p0 = EXP2(sa[cf][0] - m_run), p1 = EXP2(sa[cf][1] - m_run);
      float p2 = EXP2(sa[cf][2] - m_run), p3 = EXP2(sa[cf][3] - m_run);
      if (cf & 1) rs1 += (p0 + p1) + (p2 + p3);
      else rs0 += (p0 + p1) + (p2 + p3);
      pb[cf][0] = (f16)p0; pb[cf][1] = (f16)p1;
      pb[cf][2] = (f16)p2; pb[cf][3] = (f16)p3;
    }
    float rs = rs0 + rs1;
    rs += __shfl_xor(rs, 16);
    rs += __shfl_xor(rs, 32);
    l_run += rs;

    // O^T += V^T * P^T  (16x16x16: P^T D-layout == B-layout)
    __builtin_amdgcn_s_setprio(1);
#pragma unroll
    for (int hf = 0; hf < 4; ++hf) {
      const int row = hf * 16 + ll;
      const f16* vr = &Vl[cur][row * 64];
#pragma unroll
      for (int cf = 0; cf < 4; ++cf) {
        f16x4 va = *reinterpret_cast<const f16x4*>(
            &vr[((2 * cf + (lh >> 1)) ^ (ll & 7)) * 8 + (lh & 1) * 4]);
        acc[hf] = MFMA16(va, pb[cf], acc[hf]);
      }
    }
    __builtin_amdgcn_s_setprio(0);
    __syncthreads();
  }

  const float inv = 1.f / fmaxf(l_run, 1e-30f);
  const int q = q0 + wv * 16 + ll;
  f16* op = (half ? Op1 : Op0) + (size_t)(b * Sz + q) * (Hz * HSz) + h * HSz;
#pragma unroll
  for (int hf = 0; hf < 4; ++hf) {
    f16x4 ov;
#pragma unroll
    for (int i = 0; i < 4; ++i) ov[i] = (f16)(acc[hf][i] * inv);
    *reinterpret_cast<f16x4*>(&op[hf * 16 + 4 * lh]) = ov;
  }
  if (lh == 0) {
    float2 v; v.x = m_run; v.y = l_run;
    ml[(size_t)half * (Bz * Hz * Sz) + (size_t)bh * Sz + q] = v;
  }
}

// ---------------- combine the two K-split halves ----------------
__global__ __launch_bounds__(256) void k_comb(const f16* __restrict__ Op0,
                                              const f16* __restrict__ Op1,
                                              const float2* __restrict__ ml,
                                              f16* __restrict__ Ah) {
  const int idx = blockIdx.x * 256 + threadIdx.x;  // one f16x8 per thread
  const size_t e = (size_t)idx * 8;
  const int row = (int)(e >> 10);          // b*Sz + tok
  const int h = ((int)e >> 6) & 15;
  const int q = row & (Sz - 1), b = row >> 11;
  const size_t mli = (size_t)(b * Hz + h) * Sz + q;
  const float2 a = ml[mli];
  const float2 c = ml[(size_t)(Bz * Hz * Sz) + mli];
  const float mm = fmaxf(a.x, c.x);
  float w0 = a.y * EXP2(a.x - mm), w1 = c.y * EXP2(c.x - mm);
  const float inv = 1.f / (w0 + w1);
  w0 *= inv; w1 *= inv;
  f16x8 o0 = *reinterpret_cast<const f16x8*>(&Op0[e]);
  f16x8 o1 = *reinterpret_cast<const f16x8*>(&Op1[e]);
  f16x8 o;
#pragma unroll
  for (int i = 0; i < 8; ++i) o[i] = (f16)((float)o0[i] * w0 + (float)o1[i] * w1);
  *reinterpret_cast<f16x8*>(&Ah[e]) = o;
}

extern "C" void kernel_launch(void* const* d_in, const int* in_sizes, int n_in,
                              void* d_out, int out_size, void* d_ws, size_t ws_size,
                              hipStream_t stream) {
  const float* query = (const float*)d_in[0];
  const float* key   = (const float*)d_in[1];
  const float* value = (const float*)d_in[2];
  const float* Wq = (const float*)d_in[3];
  const float* bq = (const float*)d_in[4];
  const float* Wk = (const float*)d_in[5];
  const float* bk = (const float*)d_in[6];
  const float* Wv = (const float*)d_in[7];
  const float* bv = (const float*)d_in[8];
  const float* Wo = (const float*)d_in[9];
  const float* bo = (const float*)d_in[10];
  const int* qm = (const int*)d_in[11];
  const int* vm = (const int*)d_in[12];

  // workspace layout (f16 elements)
  f16* Xq  = (f16*)d_ws;            // later reused: Op1 (attn partial, half 1)
  f16* Xk  = Xq + 4194304;          // later reused: ml (float2[2][65536])
  f16* Xv  = Xk + 4194304;
  f16* Wqh = Xv + 4194304;
  f16* Wkh = Wqh + 1048576;
  f16* Wvh = Wkh + 1048576;
  f16* Woh = Wvh + 1048576;
  f16* Qh  = Woh + 1048576;
  f16* Kh  = Qh + 4194304;
  f16* Vth = Kh + 4194304;
  f16* Ah  = Vth + 4194304;         // Op0 (attn partial, half 0), then merged
  float* vmbias = (float*)(Ah + 4194304);  // f32[4096]
  f16* Op1 = Xq;
  float2* ml = (float2*)Xk;

  dim3 cg(4096, 3);
  k_cvt3<<<cg, 256, 0, stream>>>(query, key, value, Xq, Xk, Xv);
  k_mask<<<16, 256, 0, stream>>>(vm, vmbias);

  dim3 wg(32, 32, 4);
  k_wsplit4<<<wg, 256, 0, stream>>>(Wq, Wk, Wv, Wo, Wqh, Wkh, Wvh, Woh);

  dim3 gq(Dz / BNg, Mz / BMg, 3);  // (8, 32, 3)
  k_gemm_qkv<<<gq, 512, 0, stream>>>(Xq, Xk, Xv, Wqh, Wkh, Wvh, bq, bk, bv,
                                     Qh, Kh, Vth);

  dim3 ag(Sz / QB, Bz * Hz, KSPLIT);  // (16, 32, 2)
  k_attn<<<ag, 512, 0, stream>>>(Qh, Kh, Vth, vmbias, Ah, Op1, ml);

  k_comb<<<Mz * Dz / (256 * 8), 256, 0, stream>>>(Ah, Op1, ml, Ah);

  dim3 gg(Dz / BNg, Mz / BMg);  // (8, 32)
  k_gemm_o<<<gg, 512, 0, stream>>>(Ah, Woh, bo, (float*)d_out, qm);
}

// Round 7
// 148.157 us; speedup vs baseline: 1.1268x; 1.1268x over previous
//
#include <hip/hip_runtime.h>

#define Bz 2
#define Sz 2048
#define Dz 1024
#define Hz 16
#define HSz 64
#define Mz 4096
#define NEGB (-1e30f)
#define QSCALE (0.125f * 1.44269504088896f)  // fold 1/sqrt(64) and log2(e) into Q

typedef _Float16 f16;
typedef _Float16 f16x8 __attribute__((ext_vector_type(8)));
typedef _Float16 f16x4 __attribute__((ext_vector_type(4)));
typedef float f32x4 __attribute__((ext_vector_type(4)));

#define MFMA32(a, b, c) __builtin_amdgcn_mfma_f32_16x16x32_f16((a), (b), (c), 0, 0, 0)
#define MFMA16(a, b, c) __builtin_amdgcn_mfma_f32_16x16x16f16((a), (b), (c), 0, 0, 0)
#define EXP2(x) __builtin_amdgcn_exp2f(x)

__device__ __forceinline__ void gload16(const void* g, void* l) {
  __builtin_amdgcn_global_load_lds(
      (const __attribute__((address_space(1))) unsigned int*)(unsigned long long)g,
      (__attribute__((address_space(3))) unsigned int*)(unsigned int)(unsigned long long)l,
      16, 0, 0);
}
__device__ __forceinline__ void gload4(const void* g, void* l) {
  __builtin_amdgcn_global_load_lds(
      (const __attribute__((address_space(1))) unsigned int*)(unsigned long long)g,
      (__attribute__((address_space(3))) unsigned int*)(unsigned int)(unsigned long long)l,
      4, 0, 0);
}

// ---------------- fp32 -> fp16 convert, 3 tensors in one dispatch ----------------
__global__ __launch_bounds__(256) void k_cvt3(const float* __restrict__ a,
                                              const float* __restrict__ b,
                                              const float* __restrict__ c,
                                              f16* __restrict__ oa,
                                              f16* __restrict__ ob,
                                              f16* __restrict__ oc) {
  const float* in = blockIdx.y == 0 ? a : blockIdx.y == 1 ? b : c;
  f16* out = blockIdx.y == 0 ? oa : blockIdx.y == 1 ? ob : oc;
  int i = (blockIdx.x * 256 + threadIdx.x) * 4;
  f32x4 v = *reinterpret_cast<const f32x4*>(in + i);
  f16x4 o;
  o[0] = (f16)v[0]; o[1] = (f16)v[1]; o[2] = (f16)v[2]; o[3] = (f16)v[3];
  *reinterpret_cast<f16x4*>(out + i) = o;
}

// ---------------- v_mask -> f32 additive bias (exp2 domain) ----------------
__global__ __launch_bounds__(256) void k_mask(const int* __restrict__ vm,
                                              float* __restrict__ out) {
  int i = blockIdx.x * 256 + threadIdx.x;
  if (i < Bz * Sz) out[i] = vm[i] ? 0.f : NEGB;
}

// ---------------- W [K][N] fp32 -> Wt [N][K] fp16, 4 weights in one dispatch ----------------
__global__ __launch_bounds__(256) void k_wsplit4(
    const float* __restrict__ W0, const float* __restrict__ W1,
    const float* __restrict__ W2, const float* __restrict__ W3,
    f16* __restrict__ T0, f16* __restrict__ T1, f16* __restrict__ T2,
    f16* __restrict__ T3) {
  const int z = blockIdx.z;
  const float* W = z == 0 ? W0 : z == 1 ? W1 : z == 2 ? W2 : W3;
  f16* T = z == 0 ? T0 : z == 1 ? T1 : z == 2 ? T2 : T3;
  __shared__ float t[32][33];
  const int tx = threadIdx.x & 31, ty = threadIdx.x >> 5;
  const int n0 = blockIdx.x * 32, k0 = blockIdx.y * 32;
#pragma unroll
  for (int r = 0; r < 4; ++r)
    t[ty * 4 + r][tx] = W[(size_t)(k0 + ty * 4 + r) * Dz + n0 + tx];
  __syncthreads();
#pragma unroll
  for (int r = 0; r < 4; ++r)
    T[(size_t)(n0 + ty * 4 + r) * Dz + k0 + tx] = (f16)t[tx][ty * 4 + r];
}

// ---------------- GEMM main-loop (shared by QKV / O kernels) ----------------
#define BMg 128
#define BNg 128
#define BKg 64

#define GEMM_MAINLOOP(Aptr, Bptr)                                              \
  f32x4 acc[4][2] = {};                                                        \
  auto stage = [&](int kt, int buf) {                                          \
    const int k0 = kt * BKg;                                                   \
    _Pragma("unroll") for (int j = 0; j < 2; ++j) {                            \
      int c = j * 512 + t;                                                     \
      int row = c >> 3, p = c & 7;                                             \
      int ke = (p ^ (row & 7)) * 8;                                            \
      gload16(Aptr + (size_t)(m0 + row) * Dz + k0 + ke,                        \
              (char*)&As[buf][0] + c * 16);                                    \
      gload16(Bptr + (size_t)(n0 + row) * Dz + k0 + ke,                        \
              (char*)&Bs[buf][0] + c * 16);                                    \
    }                                                                          \
  };                                                                           \
  stage(0, 0);                                                                 \
  __syncthreads();                                                             \
  for (int kt = 0; kt < Dz / BKg; ++kt) {                                      \
    const int cur = kt & 1;                                                    \
    if (kt + 1 < Dz / BKg) stage(kt + 1, cur ^ 1);                             \
    __builtin_amdgcn_s_setprio(1);                                             \
    _Pragma("unroll") for (int ks = 0; ks < 2; ++ks) {                         \
      f16x8 af[4], bf[2];                                                      \
      _Pragma("unroll") for (int fr = 0; fr < 4; ++fr) {                       \
        const int row = wr * 64 + fr * 16 + ll;                                \
        af[fr] = *reinterpret_cast<const f16x8*>(                              \
            &As[cur][row * 64 + (((ks * 4 + lh) ^ (row & 7)) * 8)]);           \
      }                                                                        \
      _Pragma("unroll") for (int fc = 0; fc < 2; ++fc) {                       \
        const int col = wc * 32 + fc * 16 + ll;                                \
        bf[fc] = *reinterpret_cast<const f16x8*>(                              \
            &Bs[cur][col * 64 + (((ks * 4 + lh) ^ (col & 7)) * 8)]);           \
      }                                                                        \
      _Pragma("unroll") for (int fr = 0; fr < 4; ++fr)                         \
          _Pragma("unroll") for (int fc = 0; fc < 2; ++fc)                     \
              acc[fr][fc] = MFMA32(af[fr], bf[fc], acc[fr][fc]);               \
    }                                                                          \
    __builtin_amdgcn_s_setprio(0);                                             \
    __syncthreads();                                                           \
  }

// Merged Q/K/V projection GEMM: blockIdx.z selects input/weight/output.
__global__ __launch_bounds__(512) void k_gemm_qkv(
    const f16* __restrict__ Xq, const f16* __restrict__ Xk,
    const f16* __restrict__ Xv, const f16* __restrict__ Wq,
    const f16* __restrict__ Wk, const f16* __restrict__ Wv,
    const float* __restrict__ bq, const float* __restrict__ bk,
    const float* __restrict__ bv, f16* __restrict__ Qh, f16* __restrict__ Kh,
    f16* __restrict__ Vth) {
  __shared__ f16 As[2][BMg * BKg];
  __shared__ f16 Bs[2][BNg * BKg];
  const int z = blockIdx.z;
  const f16* A = z == 0 ? Xq : z == 1 ? Xk : Xv;
  const f16* Bt = z == 0 ? Wq : z == 1 ? Wk : Wv;
  const float* bias = z == 0 ? bq : z == 1 ? bk : bv;
  f16* outh = z == 0 ? Qh : z == 1 ? Kh : Vth;
  const float oscale = z == 0 ? QSCALE : 1.0f;
  const int t = threadIdx.x, lane = t & 63, wv = t >> 6;
  const int ll = lane & 15, lh = lane >> 4;
  const int m0 = blockIdx.y * BMg, n0 = blockIdx.x * BNg;
  const int wr = wv >> 2, wc = wv & 3;

  GEMM_MAINLOOP(A, Bt)

#pragma unroll
  for (int fc = 0; fc < 2; ++fc) {
    const int n = n0 + wc * 32 + fc * 16 + ll;
    const float bn = bias[n];
#pragma unroll
    for (int fr = 0; fr < 4; ++fr)
#pragma unroll
      for (int i = 0; i < 4; ++i) {
        const int m = m0 + wr * 64 + fr * 16 + lh * 4 + i;
        float v = (acc[fr][fc][i] + bn) * oscale;
        if (z < 2) {
          outh[((size_t)((m >> 11) * Hz + (n >> 6))) * (Sz * HSz) +
               (size_t)(m & (Sz - 1)) * HSz + (n & 63)] = (f16)v;
        } else {
          outh[((size_t)((m >> 11) * Hz + (n >> 6))) * (HSz * Sz) +
               (size_t)(n & 63) * Sz + (m & (Sz - 1))] = (f16)v;
        }
      }
  }
}

// Output projection GEMM: f32 out, * q_mask[row]
__global__ __launch_bounds__(512) void k_gemm_o(
    const f16* __restrict__ A, const f16* __restrict__ Bt,
    const float* __restrict__ bias, float* __restrict__ outf,
    const int* __restrict__ qmask) {
  __shared__ f16 As[2][BMg * BKg];
  __shared__ f16 Bs[2][BNg * BKg];
  const int t = threadIdx.x, lane = t & 63, wv = t >> 6;
  const int ll = lane & 15, lh = lane >> 4;
  const int m0 = blockIdx.y * BMg, n0 = blockIdx.x * BNg;
  const int wr = wv >> 2, wc = wv & 3;

  GEMM_MAINLOOP(A, Bt)

#pragma unroll
  for (int fc = 0; fc < 2; ++fc) {
    const int n = n0 + wc * 32 + fc * 16 + ll;
    const float bn = bias[n];
#pragma unroll
    for (int fr = 0; fr < 4; ++fr)
#pragma unroll
      for (int i = 0; i < 4; ++i) {
        const int m = m0 + wr * 64 + fr * 16 + lh * 4 + i;
        outf[(size_t)m * Dz + n] = (acc[fr][fc][i] + bn) * (float)qmask[m];
      }
  }
}

// ---------------- flash attention, S^T structure, 32 queries/wave ----------------
// Q,K: [bh][token][hs] f16; Vt: [bh][hs][token] f16; vmb: [b][token] f32 bias.
// 4 waves x 32 queries = QB 128. Each wave runs TWO 16-query fragment sets that
// SHARE the K/V LDS fragment reads (halves LDS bytes per query - LDS-BW bound).
// S^T = mfma32(K_frag, Q_frag): lane holds 16 key-scores of one query per set.
// Mask bias initializes the accumulator. P^T D-layout == B-layout of 16x16x16.
#define QB 128
#define KBc 64
#define NT (Sz / KBc)

__global__ __launch_bounds__(256, 4) void k_attn(
    const f16* __restrict__ Q, const f16* __restrict__ K,
    const f16* __restrict__ Vt, const float* __restrict__ vmb,
    f16* __restrict__ attnA) {
  __shared__ f16 Kl[2][KBc * 64];
  __shared__ f16 Vl[2][HSz * 64];
  __shared__ float mbl[2][KBc];
  const int t = threadIdx.x, lane = t & 63, wv = t >> 6;  // wv 0..3
  const int ll = lane & 15, lh = lane >> 4;
  const int bh = blockIdx.y, b = bh >> 4, h = bh & 15;
  const int q0 = blockIdx.x * QB + wv * 32;
  const size_t base = (size_t)bh * Sz * HSz;

  f16x8 qf[2][2];
#pragma unroll
  for (int qs = 0; qs < 2; ++qs) {
    const f16* Qb = Q + base + (size_t)(q0 + qs * 16 + ll) * HSz;
    qf[qs][0] = *reinterpret_cast<const f16x8*>(&Qb[lh * 8]);
    qf[qs][1] = *reinterpret_cast<const f16x8*>(&Qb[32 + lh * 8]);
  }

  f32x4 acc0[4] = {}, acc1[4] = {};
  float m_run0 = NEGB, l_run0 = 0.f, m_run1 = NEGB, l_run1 = 0.f;

  // stage tile key0 into buffer buf (256 threads: 2 K + 2 V granule-chunks each)
  auto stage = [&](int key0, int buf) {
#pragma unroll
    for (int j = 0; j < 2; ++j) {
      int c = j * 256 + t;
      int r = c >> 3, p = c & 7, ps = (p ^ (r & 7)) * 8;
      gload16(K + base + (size_t)(key0 + r) * HSz + ps, (char*)&Kl[buf][0] + c * 16);
      gload16(Vt + base + (size_t)r * Sz + key0 + ps, (char*)&Vl[buf][0] + c * 16);
    }
    if (wv == 0)
      gload4(vmb + b * Sz + key0 + lane, (char*)&mbl[buf][0] + lane * 4);
  };

  // in-register online softmax for one 16-query fragment set
  auto softmax = [&](f32x4 (&sa)[4], float& m_run, float& l_run, f32x4 (&acc)[4],
                     f16x4 (&pb)[4]) {
    float t0 = fmaxf(fmaxf(sa[0][0], sa[0][1]), sa[0][2]);
    float t1 = fmaxf(fmaxf(sa[0][3], sa[1][0]), sa[1][1]);
    float t2 = fmaxf(fmaxf(sa[1][2], sa[1][3]), sa[2][0]);
    float t3 = fmaxf(fmaxf(sa[2][1], sa[2][2]), sa[2][3]);
    float t4 = fmaxf(fmaxf(sa[3][0], sa[3][1]), sa[3][2]);
    float mx = fmaxf(fmaxf(fmaxf(t0, t1), fmaxf(t2, t3)), fmaxf(t4, sa[3][3]));
    mx = fmaxf(mx, __shfl_xor(mx, 16));
    mx = fmaxf(mx, __shfl_xor(mx, 32));
    if (__any(mx > m_run + 8.f)) {
      const float nm = fmaxf(m_run, mx);
      const float sc = EXP2(m_run - nm);
      m_run = nm;
      l_run *= sc;
#pragma unroll
      for (int hf = 0; hf < 4; ++hf)
#pragma unroll
        for (int i = 0; i < 4; ++i) acc[hf][i] *= sc;
    }
    float rs0 = 0.f, rs1 = 0.f;
#pragma unroll
    for (int cf = 0; cf < 4; ++cf) {
      float p0 = EXP2(sa[cf][0] - m_run), p1 = EXP2(sa[cf][1] - m_run);
      float p2 = EXP2(sa[cf][2] - m_run), p3 = EXP2(sa[cf][3] - m_run);
      if (cf & 1) rs1 += (p0 + p1) + (p2 + p3);
      else rs0 += (p0 + p1) + (p2 + p3);
      pb[cf][0] = (f16)p0; pb[cf][1] = (f16)p1;
      pb[cf][2] = (f16)p2; pb[cf][3] = (f16)p3;
    }
    float rs = rs0 + rs1;
    rs += __shfl_xor(rs, 16);
    rs += __shfl_xor(rs, 32);
    l_run += rs;
  };

  stage(0, 0);
  __syncthreads();

  for (int kt = 0; kt < NT; ++kt) {
    const int cur = kt & 1;
    if (kt + 1 < NT) stage((kt + 1) * KBc, cur ^ 1);

    // S^T = K * Q^T for both query sets; K fragments read ONCE, used twice.
    f32x4 sa0[4], sa1[4];
#pragma unroll
    for (int cf = 0; cf < 4; ++cf) {
      f32x4 mb = *reinterpret_cast<const f32x4*>(&mbl[cur][cf * 16 + lh * 4]);
      sa0[cf] = mb;
      sa1[cf] = mb;
    }
    __builtin_amdgcn_s_setprio(1);
#pragma unroll
    for (int cf = 0; cf < 4; ++cf) {
      const int row = cf * 16 + ll;
      const f16* kr = &Kl[cur][row * 64];
      f16x8 ka0 = *reinterpret_cast<const f16x8*>(&kr[(lh ^ (ll & 7)) * 8]);
      f16x8 ka1 = *reinterpret_cast<const f16x8*>(&kr[((4 + lh) ^ (ll & 7)) * 8]);
      sa0[cf] = MFMA32(ka0, qf[0][0], sa0[cf]);
      sa0[cf] = MFMA32(ka1, qf[0][1], sa0[cf]);
      sa1[cf] = MFMA32(ka0, qf[1][0], sa1[cf]);
      sa1[cf] = MFMA32(ka1, qf[1][1], sa1[cf]);
    }
    __builtin_amdgcn_s_setprio(0);

    f16x4 pb0[4], pb1[4];
    softmax(sa0, m_run0, l_run0, acc0, pb0);
    softmax(sa1, m_run1, l_run1, acc1, pb1);

    // O^T += V^T * P^T for both sets; V fragments read ONCE, used twice.
    __builtin_amdgcn_s_setprio(1);
#pragma unroll
    for (int hf = 0; hf < 4; ++hf) {
      const int row = hf * 16 + ll;
      const f16* vr = &Vl[cur][row * 64];
#pragma unroll
      for (int cf = 0; cf < 4; ++cf) {
        f16x4 va = *reinterpret_cast<const f16x4*>(
            &vr[((2 * cf + (lh >> 1)) ^ (ll & 7)) * 8 + (lh & 1) * 4]);
        acc0[hf] = MFMA16(va, pb0[cf], acc0[hf]);
        acc1[hf] = MFMA16(va, pb1[cf], acc1[hf]);
      }
    }
    __builtin_amdgcn_s_setprio(0);
    __syncthreads();  // drains vmcnt: next buffer staged; cur safe to overwrite
  }

#pragma unroll
  for (int qs = 0; qs < 2; ++qs) {
    const float l_run = qs ? l_run1 : l_run0;
    const float inv = 1.f / fmaxf(l_run, 1e-30f);
    const int q = q0 + qs * 16 + ll;
    f16* orow = attnA + (size_t)(b * Sz + q) * (Hz * HSz) + h * HSz;
#pragma unroll
    for (int hf = 0; hf < 4; ++hf) {
      const f32x4& a = qs ? acc1[hf] : acc0[hf];
      f16x4 ov;
#pragma unroll
      for (int i = 0; i < 4; ++i) ov[i] = (f16)(a[i] * inv);
      *reinterpret_cast<f16x4*>(&orow[hf * 16 + 4 * lh]) = ov;
    }
  }
}

extern "C" void kernel_launch(void* const* d_in, const int* in_sizes, int n_in,
                              void* d_out, int out_size, void* d_ws, size_t ws_size,
                              hipStream_t stream) {
  const float* query = (const float*)d_in[0];
  const float* key   = (const float*)d_in[1];
  const float* value = (const float*)d_in[2];
  const float* Wq = (const float*)d_in[3];
  const float* bq = (const float*)d_in[4];
  const float* Wk = (const float*)d_in[5];
  const float* bk = (const float*)d_in[6];
  const float* Wv = (const float*)d_in[7];
  const float* bv = (const float*)d_in[8];
  const float* Wo = (const float*)d_in[9];
  const float* bo = (const float*)d_in[10];
  const int* qm = (const int*)d_in[11];
  const int* vm = (const int*)d_in[12];

  // workspace layout (f16 elements)
  f16* Xq  = (f16*)d_ws;
  f16* Xk  = Xq + 4194304;
  f16* Xv  = Xk + 4194304;
  f16* Wqh = Xv + 4194304;
  f16* Wkh = Wqh + 1048576;
  f16* Wvh = Wkh + 1048576;
  f16* Woh = Wvh + 1048576;
  f16* Qh  = Woh + 1048576;
  f16* Kh  = Qh + 4194304;
  f16* Vth = Kh + 4194304;
  f16* Ah  = Vth + 4194304;
  float* vmbias = (float*)(Ah + 4194304);  // f32[4096]

  dim3 cg(4096, 3);
  k_cvt3<<<cg, 256, 0, stream>>>(query, key, value, Xq, Xk, Xv);
  k_mask<<<16, 256, 0, stream>>>(vm, vmbias);

  dim3 wg(32, 32, 4);
  k_wsplit4<<<wg, 256, 0, stream>>>(Wq, Wk, Wv, Wo, Wqh, Wkh, Wvh, Woh);

  dim3 gq(Dz / BNg, Mz / BMg, 3);  // (8, 32, 3)
  k_gemm_qkv<<<gq, 512, 0, stream>>>(Xq, Xk, Xv, Wqh, Wkh, Wvh, bq, bk, bv,
                                     Qh, Kh, Vth);

  dim3 ag(Sz / QB, Bz * Hz);  // (16, 32)
  k_attn<<<ag, 256, 0, stream>>>(Qh, Kh, Vth, vmbias, Ah);

  dim3 gg(Dz / BNg, Mz / BMg);  // (8, 32)
  k_gemm_o<<<gg, 512, 0, stream>>>(Ah, Woh, bo, (float*)d_out, qm);
}